// Round 4
// baseline (115.026 us; speedup 1.0000x reference)
//
#include <hip/hip_runtime.h>
#include <math.h>

#define B 512
#define N 256
#define E 1024
#define D 256
#define H 256
#define C 8
#define U 64

// ---------------------------------------------------------------------------
// Mask dtype sniffing: flag 0 = int32 words, 1 = byte-packed bool, 2 = float32
// ---------------------------------------------------------------------------
__device__ __forceinline__ float mask_val(const void* m, long i, int flag) {
    if (flag == 1) return ((const unsigned char*)m)[i] ? 1.f : 0.f;
    if (flag == 2) return (((const float*)m)[i] != 0.f) ? 1.f : 0.f;
    return ((const int*)m)[i] ? 1.f : 0.f;
}

__device__ __forceinline__ float rlf(float v, int l) {
    return __int_as_float(__builtin_amdgcn_readlane(__float_as_int(v), l));
}

// block-wide sum reduction (256 threads)
__device__ __forceinline__ float block_sum(float v, float* red) {
    int t = threadIdx.x;
    red[t] = v; __syncthreads();
    for (int s = 128; s > 0; s >>= 1) {
        if (t < s) red[t] += red[t + s];
        __syncthreads();
    }
    float r = red[0]; __syncthreads();
    return r;
}

// ---------------------------------------------------------------------------
// k_h: per-batch trunk, 2 rows/block, 512 threads, grid=256.
// Block 0 also sniffs the mask dtype into *flag.
// ---------------------------------------------------------------------------
__global__ __launch_bounds__(512) void k_h(
    const float* __restrict__ feat,
    const float* __restrict__ Wc1, const float* __restrict__ bc1,
    const float* __restrict__ Wc2, const float* __restrict__ bc2,
    const float* __restrict__ Wn1, const float* __restrict__ bn1,
    const float* __restrict__ We1, const float* __restrict__ be1,
    const float* __restrict__ Wg,  const float* __restrict__ bg,
    const float* __restrict__ margin, const float* __restrict__ brisk,
    const unsigned int* __restrict__ amask_words,
    float* __restrict__ base_n, float* __restrict__ base_e,
    float* __restrict__ out_gate, int* __restrict__ flag)
{
    __shared__ __align__(16) float sF[2][256];
    __shared__ __align__(16) float sH[2][256];
    __shared__ float red[512];
    __shared__ int cls0, cls1;

    int t = threadIdx.x;
    int w = t >> 8;        // 0/1: row in P1/P2, matrix in P3
    int c = t & 255;
    int b0 = blockIdx.x * 2;
    int b = b0 + w;

    if (blockIdx.x == 0) {
        if (t == 0) { cls0 = 0; cls1 = 0; }
        __syncthreads();
        if (t < 256) {
            unsigned int wd = amask_words[t];
            if (wd != 0u && wd != 1u) {
                if (wd == 0x3f800000u) atomicOr(&cls1, 1);
                else                   atomicOr(&cls0, 1);
            }
        }
        __syncthreads();
        if (t == 0) *flag = cls0 ? 1 : (cls1 ? 2 : 0);
    }

    sF[w][c] = feat[(long)b * D + c];
    __syncthreads();

    // ---- P1: relu(feat @ Wc1 + bc1) -> sH ----
    {
        float acc[4] = {bc1[c], 0.f, 0.f, 0.f};
        const float* Wp = Wc1 + c;
        for (int d0 = 0; d0 < D; d0 += 16) {
            float wv[16];
            #pragma unroll
            for (int k = 0; k < 16; k++) wv[k] = Wp[(long)(d0 + k) * H];
            #pragma unroll
            for (int k = 0; k < 16; k++)
                acc[k & 3] = fmaf(sF[w][d0 + k], wv[k], acc[k & 3]);
        }
        sH[w][c] = fmaxf((acc[0] + acc[1]) + (acc[2] + acc[3]), 0.f);
    }
    __syncthreads();

    // ---- P2: h = relu(A @ Wc2 + bc2) -> sF ----
    {
        float acc[4] = {bc2[c], 0.f, 0.f, 0.f};
        const float* Wp = Wc2 + c;
        for (int d0 = 0; d0 < H; d0 += 16) {
            float wv[16];
            #pragma unroll
            for (int k = 0; k < 16; k++) wv[k] = Wp[(long)(d0 + k) * H];
            #pragma unroll
            for (int k = 0; k < 16; k++)
                acc[k & 3] = fmaf(sH[w][d0 + k], wv[k], acc[k & 3]);
        }
        float a = fmaxf((acc[0] + acc[1]) + (acc[2] + acc[3]), 0.f);
        __syncthreads();
        sF[w][c] = a;                 // sF now holds h for both rows
    }
    __syncthreads();

    // ---- gate per row ----
    red[t] = sF[w][c] * Wg[c];
    __syncthreads();
    for (int s = 128; s > 0; s >>= 1) {
        if (c < s) red[t] += red[t + s];
        __syncthreads();
    }
    if (c == 0) {
        float lg = 1.f / (1.f + expf(-(red[t] + bg[0])));
        out_gate[b] = ((margin[b] < 0.2f) || (brisk[b] > 0.6f) || (lg > 0.5f)) ? 1.f : 0.f;
    }

    // ---- P3: base_n / base_e (thread-half = matrix, both rows) ----
    {
        const float* W3  = w ? (We1 + c) : (Wn1 + c);
        float bias       = w ? be1[c]    : bn1[c];
        float* dst       = w ? base_e    : base_n;
        float aA[2] = {bias, 0.f};
        float aB[2] = {bias, 0.f};
        for (int d0 = 0; d0 < H; d0 += 16) {
            float wv[16];
            #pragma unroll
            for (int k = 0; k < 16; k++) wv[k] = W3[(long)(d0 + k) * H];
            #pragma unroll
            for (int k = 0; k < 16; k++) {
                aA[k & 1] = fmaf(sF[0][d0 + k], wv[k], aA[k & 1]);
                aB[k & 1] = fmaf(sF[1][d0 + k], wv[k], aB[k & 1]);
            }
        }
        dst[(long)b0 * H + c]       = aA[0] + aA[1];
        dst[(long)(b0 + 1) * H + c] = aB[0] + aB[1];
    }
}

// ---------------------------------------------------------------------------
// k_ne: merged node+edge refinement. 256 threads, 4 items/thread.
// Blocks [0,128): node, 4 rows (one per wave). Blocks [128,640): edge, 1 row.
// Weights live in per-lane VGPRs (lane l of chunk jb holds weights of
// j = jb*64+l); broadcast per-j via v_readlane. No LDS/loads in the j-loop.
// Rows with gate==0 skip the MLP entirely (exact: delta contributes 0).
// ---------------------------------------------------------------------------
__global__ __launch_bounds__(256) void k_ne(
    // node inputs
    const float* __restrict__ cs, const float* __restrict__ coords,
    const float* __restrict__ unc, const int* __restrict__ actions,
    const void* __restrict__ amask,
    const float* __restrict__ Wn1, const float* __restrict__ Wn2,
    const float* __restrict__ bn2, const float* __restrict__ base_n,
    // edge inputs
    const float* __restrict__ es, const int* __restrict__ edges,
    const void* __restrict__ emask,
    const float* __restrict__ We1, const float* __restrict__ We2,
    const float* __restrict__ be2, const float* __restrict__ base_e,
    // common
    const float* __restrict__ gate, const int* __restrict__ flagp,
    float* __restrict__ out0, float* __restrict__ out2)
{
    __shared__ __align__(16) float sC[256][8];   // edge branch only
    int t = threadIdx.x;
    int w = t >> 6, lane = t & 63;
    int flag = *flagp;

    if (blockIdx.x < 128) {
        // ================= NODE (no barriers in this branch) =================
        int b = blockIdx.x * 4 + w;              // one row per wave
        float g = gate[b];

        if (g == 0.f) {
            // delta contributes nothing: raw = cs * am
            #pragma unroll
            for (int q = 0; q < 4; q++) {
                int n = q * 64 + lane;
                float am = mask_val(amask, (long)b * N + n, flag);
                out0[(long)b * N + n] = cs[(long)b * N + n] * am;
            }
            return;
        }

        // per-lane weight chunk: lane l holds j = jb*64+l
        float wreg[4][11], breg[4];
        #pragma unroll
        for (int jb = 0; jb < 4; jb++) {
            int j = jb * 64 + lane;
            #pragma unroll
            for (int k = 0; k < 10; k++) wreg[jb][k] = Wn1[(long)(H + k) * H + j];
            wreg[jb][10] = Wn2[j];
            breg[jb] = base_n[(long)b * H + j];
        }
        float b2v = bn2[0];

        float f[4][10], acc[4], amv[4];
        #pragma unroll
        for (int q = 0; q < 4; q++) {
            int n = q * 64 + lane;
            const float4* cp = (const float4*)(coords + ((long)b * N + n) * C);
            float4 c0 = cp[0], c1 = cp[1];
            f[q][0] = c0.x; f[q][1] = c0.y; f[q][2] = c0.z; f[q][3] = c0.w;
            f[q][4] = c1.x; f[q][5] = c1.y; f[q][6] = c1.z; f[q][7] = c1.w;
            f[q][8] = cs[(long)b * N + n];
            int a = actions[(long)b * N + n];
            a = min(max(a, 0), U - 1);
            f[q][9] = unc[(long)b * U + a];
            amv[q] = mask_val(amask, (long)b * N + n, flag);
            acc[q] = b2v;
        }

        #pragma unroll
        for (int jb = 0; jb < 4; jb++) {
            for (int l = 0; l < 64; l++) {
                float w0 = rlf(wreg[jb][0], l), w1 = rlf(wreg[jb][1], l);
                float w2 = rlf(wreg[jb][2], l), w3 = rlf(wreg[jb][3], l);
                float w4 = rlf(wreg[jb][4], l), w5 = rlf(wreg[jb][5], l);
                float w6 = rlf(wreg[jb][6], l), w7 = rlf(wreg[jb][7], l);
                float w8 = rlf(wreg[jb][8], l), w9 = rlf(wreg[jb][9], l);
                float w2v = rlf(wreg[jb][10], l);
                float bse = rlf(breg[jb], l);
                #pragma unroll
                for (int q = 0; q < 4; q++) {
                    float zA = fmaf(f[q][0], w0, bse);
                    zA = fmaf(f[q][1], w1, zA);
                    zA = fmaf(f[q][2], w2, zA);
                    zA = fmaf(f[q][3], w3, zA);
                    zA = fmaf(f[q][4], w4, zA);
                    float zB = f[q][5] * w5;
                    zB = fmaf(f[q][6], w6, zB);
                    zB = fmaf(f[q][7], w7, zB);
                    zB = fmaf(f[q][8], w8, zB);
                    zB = fmaf(f[q][9], w9, zB);
                    acc[q] = fmaf(fmaxf(zA + zB, 0.f), w2v, acc[q]);
                }
            }
        }

        #pragma unroll
        for (int q = 0; q < 4; q++) {
            int n = q * 64 + lane;
            float am = amv[q];
            float nd = acc[q] * am;
            out0[(long)b * N + n] = (f[q][8] + g * 0.1f * nd) * am;
        }
    } else {
        // ================= EDGE (block = one row; gate uniform) =============
        int b = blockIdx.x - 128;
        float g = gate[b];

        if (g == 0.f) {
            #pragma unroll
            for (int q = 0; q < 4; q++) {
                int e = t + 256 * q;
                float em = mask_val(emask, (long)b * E + e, flag);
                out2[(long)b * E + e] = es[(long)b * E + e] * em;
            }
            return;
        }

        // stage this row's coords (8KB)
        {
            float4* sc4 = (float4*)&sC[0][0];
            const float4* g4 = (const float4*)(coords + (long)b * N * C);
            sc4[t] = g4[t];
            sc4[t + 256] = g4[t + 256];
        }

        float wreg[4][11], breg[4];
        #pragma unroll
        for (int jb = 0; jb < 4; jb++) {
            int j = jb * 64 + lane;
            #pragma unroll
            for (int k = 0; k < 10; k++) wreg[jb][k] = We1[(long)(H + k) * H + j];
            wreg[jb][10] = We2[j];
            breg[jb] = base_e[(long)b * H + j];
        }
        float b2v = be2[0];
        __syncthreads();

        float f[4][10], acc[4], emv[4];
        #pragma unroll
        for (int q = 0; q < 4; q++) {
            int e = t + 256 * q;
            int2 ev = ((const int2*)edges)[(long)b * E + e];
            int s0 = min(max(ev.x, 0), N - 1);
            int d0 = min(max(ev.y, 0), N - 1);
            #pragma unroll
            for (int k = 0; k < 8; k++) f[q][k] = sC[d0][k] - sC[s0][k];
            f[q][8] = es[(long)b * E + e];
            emv[q] = mask_val(emask, (long)b * E + e, flag);
            f[q][9] = emv[q];
            acc[q] = b2v;
        }

        #pragma unroll
        for (int jb = 0; jb < 4; jb++) {
            for (int l = 0; l < 64; l++) {
                float w0 = rlf(wreg[jb][0], l), w1 = rlf(wreg[jb][1], l);
                float w2 = rlf(wreg[jb][2], l), w3 = rlf(wreg[jb][3], l);
                float w4 = rlf(wreg[jb][4], l), w5 = rlf(wreg[jb][5], l);
                float w6 = rlf(wreg[jb][6], l), w7 = rlf(wreg[jb][7], l);
                float w8 = rlf(wreg[jb][8], l), w9 = rlf(wreg[jb][9], l);
                float w2v = rlf(wreg[jb][10], l);
                float bse = rlf(breg[jb], l);
                #pragma unroll
                for (int q = 0; q < 4; q++) {
                    float zA = fmaf(f[q][0], w0, bse);
                    zA = fmaf(f[q][1], w1, zA);
                    zA = fmaf(f[q][2], w2, zA);
                    zA = fmaf(f[q][3], w3, zA);
                    zA = fmaf(f[q][4], w4, zA);
                    float zB = f[q][5] * w5;
                    zB = fmaf(f[q][6], w6, zB);
                    zB = fmaf(f[q][7], w7, zB);
                    zB = fmaf(f[q][8], w8, zB);
                    zB = fmaf(f[q][9], w9, zB);
                    acc[q] = fmaf(fmaxf(zA + zB, 0.f), w2v, acc[q]);
                }
            }
        }

        #pragma unroll
        for (int q = 0; q < 4; q++) {
            int e = t + 256 * q;
            float re = (emv[q] != 0.f) ? (f[q][8] + g * 0.1f * acc[q]) : 0.f;
            out2[(long)b * E + e] = re;
        }
    }
}

// ---------------------------------------------------------------------------
// k_final: one batch row per block. Center scores, top-2 (+index), edge
// mean/var, uncertainty term, risk.
// ---------------------------------------------------------------------------
__global__ __launch_bounds__(256) void k_final(
    const void* __restrict__ amask, const void* __restrict__ emask,
    const int* __restrict__ actions, const float* __restrict__ unc,
    const int* __restrict__ flagp,
    float* __restrict__ out0, float* __restrict__ out1,
    const float* __restrict__ out2,
    float* __restrict__ out3, float* __restrict__ out4)
{
    __shared__ float red[256];
    __shared__ int ridx[256];
    int t = threadIdx.x;
    int b = blockIdx.x;
    int flag = *flagp;

    float am = mask_val(amask, (long)b * N + t, flag);
    float raw = out0[(long)b * N + t];

    float sum = block_sum(raw, red);
    float cnt = block_sum(am, red);
    float denom = fmaxf(cnt, 1.f);

    float rs = (raw - sum / denom) * am;
    out0[(long)b * N + t] = rs;

    float masked = (am != 0.f) ? rs : -1e9f;

    // top-1 with index (ties -> lower index)
    red[t] = masked; ridx[t] = t; __syncthreads();
    for (int s = 128; s > 0; s >>= 1) {
        if (t < s) {
            float o = red[t + s]; int oi = ridx[t + s];
            if (o > red[t] || (o == red[t] && oi < ridx[t])) { red[t] = o; ridx[t] = oi; }
        }
        __syncthreads();
    }
    float v1 = red[0]; int i1 = ridx[0]; __syncthreads();

    // top-2 value
    float m2 = (t == i1) ? -1e9f : masked;
    red[t] = m2; __syncthreads();
    for (int s = 128; s > 0; s >>= 1) {
        if (t < s) red[t] = fmaxf(red[t], red[t + s]);
        __syncthreads();
    }
    float v2 = red[0]; __syncthreads();
    float rmargin = v1 - v2;

    // uncertainty term
    int a = actions[(long)b * N + t];
    a = min(max(a, 0), U - 1);
    float su = block_sum(unc[(long)b * U + a] * am, red);
    float unc_term = su / denom;

    // edge mean / variance
    float x[4], em[4];
    float S1 = 0.f, ce = 0.f;
    #pragma unroll
    for (int q = 0; q < 4; q++) {
        long idx = (long)b * E + t + 256 * q;
        x[q] = out2[idx];
        em[q] = mask_val(emask, idx, flag);
        S1 += x[q]; ce += em[q];
    }
    float S1t = block_sum(S1, red);
    float cet = block_sum(ce, red);
    float mean = S1t / fmaxf(cet, 1.f);
    float v = 0.f;
    #pragma unroll
    for (int q = 0; q < 4; q++) {
        float dd = x[q] - mean;
        v = fmaf(em[q] * dd, dd, v);
    }
    float vt = block_sum(v, red);
    float var = vt / fmaxf(cet, 1.f);
    float evar = (cet > 1.f) ? var : 0.f;

    if (t == 0) {
        out1[b] = rmargin;
        out3[b] = (float)i1;
        float sig = 1.f / (1.f + expf(rmargin));
        float riskv = sig + 0.2f * evar + 0.1f * unc_term;
        out4[b] = fminf(fmaxf(riskv, 0.f), 1.f);
    }
}

// ---------------------------------------------------------------------------
extern "C" void kernel_launch(void* const* d_in, const int* in_sizes, int n_in,
                              void* d_out, int out_size, void* d_ws, size_t ws_size,
                              hipStream_t stream) {
    const float* feat   = (const float*)d_in[0];
    const float* cs     = (const float*)d_in[1];
    const float* marg   = (const float*)d_in[2];
    const float* brisk  = (const float*)d_in[3];
    const float* es     = (const float*)d_in[4];
    const float* coords = (const float*)d_in[5];
    const float* unc    = (const float*)d_in[6];
    const float* Wc1    = (const float*)d_in[7];
    const float* bc1    = (const float*)d_in[8];
    const float* Wc2    = (const float*)d_in[9];
    const float* bc2    = (const float*)d_in[10];
    const float* Wn1    = (const float*)d_in[11];
    const float* bn1    = (const float*)d_in[12];
    const float* Wn2    = (const float*)d_in[13];
    const float* bn2    = (const float*)d_in[14];
    const float* We1    = (const float*)d_in[15];
    const float* be1    = (const float*)d_in[16];
    const float* We2    = (const float*)d_in[17];
    const float* be2    = (const float*)d_in[18];
    const float* Wg     = (const float*)d_in[19];
    const float* bg     = (const float*)d_in[20];
    const void*  amask  = d_in[21];
    const void*  emask  = d_in[22];
    const int*   actions= (const int*)d_in[23];
    const int*   edges  = (const int*)d_in[24];

    float* out0 = (float*)d_out;           // refined_scores (B,N)
    float* out1 = out0 + (long)B * N;      // refined_margin (B,)
    float* out2 = out1 + B;                // refined_edge (B,E)
    float* out3 = out2 + (long)B * E;      // top_idx (B,) as float
    float* out4 = out3 + B;                // refined_risk (B,)
    float* out5 = out4 + B;                // refine_gate (B,)

    float* base_n = (float*)d_ws;                   // B*H
    float* base_e = base_n + (long)B * H;           // B*H
    int*   flag   = (int*)(base_e + (long)B * H);

    k_h<<<B / 2, 512, 0, stream>>>(feat, Wc1, bc1, Wc2, bc2, Wn1, bn1, We1, be1,
                                   Wg, bg, marg, brisk,
                                   (const unsigned int*)amask,
                                   base_n, base_e, out5, flag);
    k_ne<<<128 + B, 256, 0, stream>>>(cs, coords, unc, actions, amask,
                                      Wn1, Wn2, bn2, base_n,
                                      es, edges, emask,
                                      We1, We2, be2, base_e,
                                      out5, flag, out0, out2);
    k_final<<<B, 256, 0, stream>>>(amask, emask, actions, unc, flag,
                                   out0, out1, out2, out3, out4);
}

// Round 5
// 80.802 us; speedup vs baseline: 1.4236x; 1.4236x over previous
//
#include <hip/hip_runtime.h>
#include <math.h>

#define B 512
#define N 256
#define E 1024
#define D 256
#define H 256
#define C 8
#define U 64

// ---------------------------------------------------------------------------
// Mask dtype sniffing: flag 0 = int32 words, 1 = byte-packed bool, 2 = float32
// ---------------------------------------------------------------------------
__device__ __forceinline__ float mask_val(const void* m, long i, int flag) {
    if (flag == 1) return ((const unsigned char*)m)[i] ? 1.f : 0.f;
    if (flag == 2) return (((const float*)m)[i] != 0.f) ? 1.f : 0.f;
    return ((const int*)m)[i] ? 1.f : 0.f;
}

// block-wide sum reduction (256 threads)
__device__ __forceinline__ float block_sum(float v, float* red) {
    int t = threadIdx.x;
    red[t] = v; __syncthreads();
    for (int s = 128; s > 0; s >>= 1) {
        if (t < s) red[t] += red[t + s];
        __syncthreads();
    }
    float r = red[0]; __syncthreads();
    return r;
}

// ---------------------------------------------------------------------------
// k_h: per-batch trunk, 2 rows/block, 512 threads, grid=256.
// Block 0 also sniffs the mask dtype into *flag.
// ---------------------------------------------------------------------------
__global__ __launch_bounds__(512) void k_h(
    const float* __restrict__ feat,
    const float* __restrict__ Wc1, const float* __restrict__ bc1,
    const float* __restrict__ Wc2, const float* __restrict__ bc2,
    const float* __restrict__ Wn1, const float* __restrict__ bn1,
    const float* __restrict__ We1, const float* __restrict__ be1,
    const float* __restrict__ Wg,  const float* __restrict__ bg,
    const float* __restrict__ margin, const float* __restrict__ brisk,
    const unsigned int* __restrict__ amask_words,
    float* __restrict__ base_n, float* __restrict__ base_e,
    float* __restrict__ out_gate, int* __restrict__ flag)
{
    __shared__ __align__(16) float sF[2][256];
    __shared__ __align__(16) float sH[2][256];
    __shared__ float red[512];
    __shared__ int cls0, cls1;

    int t = threadIdx.x;
    int w = t >> 8;        // 0/1: row in P1/P2, matrix in P3
    int c = t & 255;
    int b0 = blockIdx.x * 2;
    int b = b0 + w;

    if (blockIdx.x == 0) {
        if (t == 0) { cls0 = 0; cls1 = 0; }
        __syncthreads();
        if (t < 256) {
            unsigned int wd = amask_words[t];
            if (wd != 0u && wd != 1u) {
                if (wd == 0x3f800000u) atomicOr(&cls1, 1);
                else                   atomicOr(&cls0, 1);
            }
        }
        __syncthreads();
        if (t == 0) *flag = cls0 ? 1 : (cls1 ? 2 : 0);
    }

    sF[w][c] = feat[(long)b * D + c];
    __syncthreads();

    // ---- P1: relu(feat @ Wc1 + bc1) -> sH ----
    {
        float acc[4] = {bc1[c], 0.f, 0.f, 0.f};
        const float* Wp = Wc1 + c;
        for (int d0 = 0; d0 < D; d0 += 16) {
            float wv[16];
            #pragma unroll
            for (int k = 0; k < 16; k++) wv[k] = Wp[(long)(d0 + k) * H];
            #pragma unroll
            for (int k = 0; k < 16; k++)
                acc[k & 3] = fmaf(sF[w][d0 + k], wv[k], acc[k & 3]);
        }
        sH[w][c] = fmaxf((acc[0] + acc[1]) + (acc[2] + acc[3]), 0.f);
    }
    __syncthreads();

    // ---- P2: h = relu(A @ Wc2 + bc2) -> sF ----
    {
        float acc[4] = {bc2[c], 0.f, 0.f, 0.f};
        const float* Wp = Wc2 + c;
        for (int d0 = 0; d0 < H; d0 += 16) {
            float wv[16];
            #pragma unroll
            for (int k = 0; k < 16; k++) wv[k] = Wp[(long)(d0 + k) * H];
            #pragma unroll
            for (int k = 0; k < 16; k++)
                acc[k & 3] = fmaf(sH[w][d0 + k], wv[k], acc[k & 3]);
        }
        float a = fmaxf((acc[0] + acc[1]) + (acc[2] + acc[3]), 0.f);
        __syncthreads();
        sF[w][c] = a;                 // sF now holds h for both rows
    }
    __syncthreads();

    // ---- gate per row ----
    red[t] = sF[w][c] * Wg[c];
    __syncthreads();
    for (int s = 128; s > 0; s >>= 1) {
        if (c < s) red[t] += red[t + s];
        __syncthreads();
    }
    if (c == 0) {
        float lg = 1.f / (1.f + expf(-(red[t] + bg[0])));
        out_gate[b] = ((margin[b] < 0.2f) || (brisk[b] > 0.6f) || (lg > 0.5f)) ? 1.f : 0.f;
    }

    // ---- P3: base_n / base_e (thread-half = matrix, both rows) ----
    {
        const float* W3  = w ? (We1 + c) : (Wn1 + c);
        float bias       = w ? be1[c]    : bn1[c];
        float* dst       = w ? base_e    : base_n;
        float aA[2] = {bias, 0.f};
        float aB[2] = {bias, 0.f};
        for (int d0 = 0; d0 < H; d0 += 16) {
            float wv[16];
            #pragma unroll
            for (int k = 0; k < 16; k++) wv[k] = W3[(long)(d0 + k) * H];
            #pragma unroll
            for (int k = 0; k < 16; k++) {
                aA[k & 1] = fmaf(sF[0][d0 + k], wv[k], aA[k & 1]);
                aB[k & 1] = fmaf(sF[1][d0 + k], wv[k], aB[k & 1]);
            }
        }
        dst[(long)b0 * H + c]       = aA[0] + aA[1];
        dst[(long)(b0 + 1) * H + c] = aB[0] + aB[1];
    }
}

// ---------------------------------------------------------------------------
// k_ne: blocks [0,512) = node row b (1 item/thread, fused centering/top-2/
// margin/riskbase); blocks [512,1024) = edge row (4 items/thread, fused
// mean/var). Weights+base packed per block into LDS [256][16]; the j-loop
// reads exactly 3 wave-uniform ds_read_b128 per j.
// ---------------------------------------------------------------------------
__global__ __launch_bounds__(256) void k_ne(
    // node inputs
    const float* __restrict__ cs, const float* __restrict__ coords,
    const float* __restrict__ unc, const int* __restrict__ actions,
    const void* __restrict__ amask,
    const float* __restrict__ Wn1, const float* __restrict__ Wn2,
    const float* __restrict__ bn2, const float* __restrict__ base_n,
    // edge inputs
    const float* __restrict__ es, const int* __restrict__ edges,
    const void* __restrict__ emask,
    const float* __restrict__ We1, const float* __restrict__ We2,
    const float* __restrict__ be2, const float* __restrict__ base_e,
    // common
    const float* __restrict__ gate, const int* __restrict__ flagp,
    float* __restrict__ out0, float* __restrict__ out1, float* __restrict__ out2,
    float* __restrict__ out3, float* __restrict__ riskbase, float* __restrict__ evar)
{
    __shared__ __align__(16) float smem[4096 + 2048];   // 16KB pack + 8KB aux
    float* pack = smem;                                   // [256][16]
    int t = threadIdx.x;
    int flag = *flagp;

    if (blockIdx.x < 512) {
        // ================= NODE: one row, 1 item/thread =================
        int b = blockIdx.x;
        float g = gate[b];
        float am = mask_val(amask, (long)b * N + t, flag);
        float csv = cs[(long)b * N + t];
        int a = actions[(long)b * N + t];
        a = min(max(a, 0), U - 1);
        float ug = unc[(long)b * U + a];

        float raw;
        if (g != 0.f) {
            // stage pack: [j][0..9]=Wn1 extras, [10]=Wn2, [11]=base_n[b]
            #pragma unroll
            for (int i = 0; i < 4; i++) {
                int lin = t + 256 * i;
                int j = lin >> 2, kq = (lin & 3) * 4;
                float4 v;
                if (kq == 0)
                    v = make_float4(Wn1[(long)(H+0)*H+j], Wn1[(long)(H+1)*H+j],
                                    Wn1[(long)(H+2)*H+j], Wn1[(long)(H+3)*H+j]);
                else if (kq == 4)
                    v = make_float4(Wn1[(long)(H+4)*H+j], Wn1[(long)(H+5)*H+j],
                                    Wn1[(long)(H+6)*H+j], Wn1[(long)(H+7)*H+j]);
                else if (kq == 8)
                    v = make_float4(Wn1[(long)(H+8)*H+j], Wn1[(long)(H+9)*H+j],
                                    Wn2[j], base_n[(long)b*H+j]);
                else
                    v = make_float4(0.f, 0.f, 0.f, 0.f);
                ((float4*)pack)[lin] = v;
            }

            const float4* cp = (const float4*)(coords + ((long)b * N + t) * C);
            float4 c0 = cp[0], c1 = cp[1];
            float f0 = c0.x, f1 = c0.y, f2 = c0.z, f3 = c0.w;
            float f4 = c1.x, f5 = c1.y, f6 = c1.z, f7 = c1.w;
            float f8 = csv, f9 = ug;
            float acc = bn2[0];
            __syncthreads();

            const float4* pk = (const float4*)pack;
            #pragma unroll 2
            for (int j = 0; j < H; j++) {
                float4 wa = pk[j*4+0];
                float4 wb = pk[j*4+1];
                float4 wc = pk[j*4+2];
                float zA = fmaf(f0, wa.x, wc.w);     // base
                zA = fmaf(f1, wa.y, zA);
                zA = fmaf(f2, wa.z, zA);
                zA = fmaf(f3, wa.w, zA);
                float zB = f4 * wb.x;
                zB = fmaf(f5, wb.y, zB);
                zB = fmaf(f6, wb.z, zB);
                zB = fmaf(f7, wb.w, zB);
                zB = fmaf(f8, wc.x, zB);
                zB = fmaf(f9, wc.y, zB);
                acc = fmaf(fmaxf(zA + zB, 0.f), wc.z, acc);
            }
            raw = (csv + g * 0.1f * (acc * am)) * am;
            __syncthreads();   // pack done; aux region free for reductions
        } else {
            raw = csv * am;
        }

        // ---- fused finalization (whole row is in this block) ----
        float* red = smem + 4096;
        int* ridx = (int*)(smem + 4096 + 256);

        float sum = block_sum(raw, red);
        float cnt = block_sum(am, red);
        float denom = fmaxf(cnt, 1.f);
        float rs = (raw - sum / denom) * am;
        out0[(long)b * N + t] = rs;

        float masked = (am != 0.f) ? rs : -1e9f;

        red[t] = masked; ridx[t] = t; __syncthreads();
        for (int s = 128; s > 0; s >>= 1) {
            if (t < s) {
                float o = red[t + s]; int oi = ridx[t + s];
                if (o > red[t] || (o == red[t] && oi < ridx[t])) { red[t] = o; ridx[t] = oi; }
            }
            __syncthreads();
        }
        float v1 = red[0]; int i1 = ridx[0]; __syncthreads();

        red[t] = (t == i1) ? -1e9f : masked; __syncthreads();
        for (int s = 128; s > 0; s >>= 1) {
            if (t < s) red[t] = fmaxf(red[t], red[t + s]);
            __syncthreads();
        }
        float v2 = red[0]; __syncthreads();
        float rmargin = v1 - v2;

        float su = block_sum(ug * am, red);

        if (t == 0) {
            out1[b] = rmargin;
            out3[b] = (float)i1;
            float sig = 1.f / (1.f + expf(rmargin));   // sigmoid(-margin)
            riskbase[b] = sig + 0.1f * (su / denom);
        }
    } else {
        // ================= EDGE: one row, 4 items/thread =================
        int b = blockIdx.x - 512;
        float g = gate[b];
        float (*sC)[8] = (float (*)[8])(smem + 4096);

        float re[4], emv[4];
        if (g != 0.f) {
            // stage coords (8KB) + pack: [j][0..7]=w0..7, [8]=w8, [9]=We2,
            // [10]=base_e[b]+w9 (emf==1 fold), [11]=pad
            {
                float4* sc4 = (float4*)&sC[0][0];
                const float4* g4 = (const float4*)(coords + (long)b * N * C);
                sc4[t] = g4[t];
                sc4[t + 256] = g4[t + 256];
            }
            #pragma unroll
            for (int i = 0; i < 4; i++) {
                int lin = t + 256 * i;
                int j = lin >> 2, kq = (lin & 3) * 4;
                float4 v;
                if (kq == 0)
                    v = make_float4(We1[(long)(H+0)*H+j], We1[(long)(H+1)*H+j],
                                    We1[(long)(H+2)*H+j], We1[(long)(H+3)*H+j]);
                else if (kq == 4)
                    v = make_float4(We1[(long)(H+4)*H+j], We1[(long)(H+5)*H+j],
                                    We1[(long)(H+6)*H+j], We1[(long)(H+7)*H+j]);
                else if (kq == 8)
                    v = make_float4(We1[(long)(H+8)*H+j], We2[j],
                                    base_e[(long)b*H+j] + We1[(long)(H+9)*H+j], 0.f);
                else
                    v = make_float4(0.f, 0.f, 0.f, 0.f);
                ((float4*)pack)[lin] = v;
            }
            float b2v = be2[0];
            __syncthreads();

            float f[4][9], acc[4];
            #pragma unroll
            for (int q = 0; q < 4; q++) {
                int e = t + 256 * q;
                int2 ev = ((const int2*)edges)[(long)b * E + e];
                int s0 = min(max(ev.x, 0), N - 1);
                int d0 = min(max(ev.y, 0), N - 1);
                #pragma unroll
                for (int k = 0; k < 8; k++) f[q][k] = sC[d0][k] - sC[s0][k];
                f[q][8] = es[(long)b * E + e];
                emv[q] = mask_val(emask, (long)b * E + e, flag);
                acc[q] = b2v;
            }

            const float4* pk = (const float4*)pack;
            #pragma unroll 2
            for (int j = 0; j < H; j++) {
                float4 wa = pk[j*4+0];
                float4 wb = pk[j*4+1];
                float4 wc = pk[j*4+2];
                #pragma unroll
                for (int q = 0; q < 4; q++) {
                    float zA = fmaf(f[q][0], wa.x, wc.z);  // base (+w9 fold)
                    zA = fmaf(f[q][1], wa.y, zA);
                    zA = fmaf(f[q][2], wa.z, zA);
                    zA = fmaf(f[q][3], wa.w, zA);
                    float zB = f[q][4] * wb.x;
                    zB = fmaf(f[q][5], wb.y, zB);
                    zB = fmaf(f[q][6], wb.z, zB);
                    zB = fmaf(f[q][7], wb.w, zB);
                    zB = fmaf(f[q][8], wc.x, zB);
                    acc[q] = fmaf(fmaxf(zA + zB, 0.f), wc.y, acc[q]);
                }
            }

            #pragma unroll
            for (int q = 0; q < 4; q++) {
                re[q] = (emv[q] != 0.f) ? (f[q][8] + g * 0.1f * acc[q]) : 0.f;
                out2[(long)b * E + t + 256 * q] = re[q];
            }
        } else {
            #pragma unroll
            for (int q = 0; q < 4; q++) {
                int e = t + 256 * q;
                emv[q] = mask_val(emask, (long)b * E + e, flag);
                re[q] = es[(long)b * E + e] * emv[q];
                out2[(long)b * E + e] = re[q];
            }
        }

        // ---- fused mean/var (two-pass; values in registers) ----
        __syncthreads();                 // sC region now reused as red
        float* red = smem + 4096;

        float S1 = 0.f, ce = 0.f;
        #pragma unroll
        for (int q = 0; q < 4; q++) { S1 += re[q]; ce += emv[q]; }
        float S1t = block_sum(S1, red);
        float cet = block_sum(ce, red);
        float mean = S1t / fmaxf(cet, 1.f);
        float v = 0.f;
        #pragma unroll
        for (int q = 0; q < 4; q++) {
            float dd = re[q] - mean;
            v = fmaf(emv[q] * dd, dd, v);
        }
        float vt = block_sum(v, red);
        if (t == 0) {
            float var = vt / fmaxf(cet, 1.f);
            evar[b] = (cet > 1.f) ? var : 0.f;
        }
    }
}

// ---------------------------------------------------------------------------
// k_risk: out4 = clip(riskbase + 0.2*evar, 0, 1)
// ---------------------------------------------------------------------------
__global__ __launch_bounds__(256) void k_risk(
    const float* __restrict__ riskbase, const float* __restrict__ evar,
    float* __restrict__ out4)
{
    int b = blockIdx.x * 256 + threadIdx.x;
    float r = riskbase[b] + 0.2f * evar[b];
    out4[b] = fminf(fmaxf(r, 0.f), 1.f);
}

// ---------------------------------------------------------------------------
extern "C" void kernel_launch(void* const* d_in, const int* in_sizes, int n_in,
                              void* d_out, int out_size, void* d_ws, size_t ws_size,
                              hipStream_t stream) {
    const float* feat   = (const float*)d_in[0];
    const float* cs     = (const float*)d_in[1];
    const float* marg   = (const float*)d_in[2];
    const float* brisk  = (const float*)d_in[3];
    const float* es     = (const float*)d_in[4];
    const float* coords = (const float*)d_in[5];
    const float* unc    = (const float*)d_in[6];
    const float* Wc1    = (const float*)d_in[7];
    const float* bc1    = (const float*)d_in[8];
    const float* Wc2    = (const float*)d_in[9];
    const float* bc2    = (const float*)d_in[10];
    const float* Wn1    = (const float*)d_in[11];
    const float* bn1    = (const float*)d_in[12];
    const float* Wn2    = (const float*)d_in[13];
    const float* bn2    = (const float*)d_in[14];
    const float* We1    = (const float*)d_in[15];
    const float* be1    = (const float*)d_in[16];
    const float* We2    = (const float*)d_in[17];
    const float* be2    = (const float*)d_in[18];
    const float* Wg     = (const float*)d_in[19];
    const float* bg     = (const float*)d_in[20];
    const void*  amask  = d_in[21];
    const void*  emask  = d_in[22];
    const int*   actions= (const int*)d_in[23];
    const int*   edges  = (const int*)d_in[24];

    float* out0 = (float*)d_out;           // refined_scores (B,N)
    float* out1 = out0 + (long)B * N;      // refined_margin (B,)
    float* out2 = out1 + B;                // refined_edge (B,E)
    float* out3 = out2 + (long)B * E;      // top_idx (B,) as float
    float* out4 = out3 + B;                // refined_risk (B,)
    float* out5 = out4 + B;                // refine_gate (B,)

    float* base_n  = (float*)d_ws;                  // B*H
    float* base_e  = base_n + (long)B * H;          // B*H
    float* riskbase= base_e + (long)B * H;          // B
    float* evar    = riskbase + B;                  // B
    int*   flag    = (int*)(evar + B);

    k_h<<<B / 2, 512, 0, stream>>>(feat, Wc1, bc1, Wc2, bc2, Wn1, bn1, We1, be1,
                                   Wg, bg, marg, brisk,
                                   (const unsigned int*)amask,
                                   base_n, base_e, out5, flag);
    k_ne<<<1024, 256, 0, stream>>>(cs, coords, unc, actions, amask,
                                   Wn1, Wn2, bn2, base_n,
                                   es, edges, emask,
                                   We1, We2, be2, base_e,
                                   out5, flag,
                                   out0, out1, out2, out3, riskbase, evar);
    k_risk<<<2, 256, 0, stream>>>(riskbase, evar, out4);
}

// Round 6
// 80.434 us; speedup vs baseline: 1.4301x; 1.0046x over previous
//
#include <hip/hip_runtime.h>
#include <math.h>

#define B 512
#define N 256
#define E 1024
#define D 256
#define H 256
#define C 8
#define U 64

#define NODE_GRID 512   // 128 row-groups x 4 j-quarters
#define EDGE_GRID 2048  // 512 rows x 4 j-quarters

// ---------------------------------------------------------------------------
// Mask dtype sniffing: flag 0 = int32 words, 1 = byte-packed bool, 2 = float32
// ---------------------------------------------------------------------------
__device__ __forceinline__ float mask_val(const void* m, long i, int flag) {
    if (flag == 1) return ((const unsigned char*)m)[i] ? 1.f : 0.f;
    if (flag == 2) return (((const float*)m)[i] != 0.f) ? 1.f : 0.f;
    return ((const int*)m)[i] ? 1.f : 0.f;
}

// block-wide sum reduction (256 threads)
__device__ __forceinline__ float block_sum(float v, float* red) {
    int t = threadIdx.x;
    red[t] = v; __syncthreads();
    for (int s = 128; s > 0; s >>= 1) {
        if (t < s) red[t] += red[t + s];
        __syncthreads();
    }
    float r = red[0]; __syncthreads();
    return r;
}

// ---------------------------------------------------------------------------
// k_h: per-batch trunk, 2 rows/block, 512 threads, grid=256.
// Also zeroes the partial-delta accumulators (node_delta ws + out2) and
// sniffs the mask dtype (block 0).
// ---------------------------------------------------------------------------
__global__ __launch_bounds__(512) void k_h(
    const float* __restrict__ feat,
    const float* __restrict__ Wc1, const float* __restrict__ bc1,
    const float* __restrict__ Wc2, const float* __restrict__ bc2,
    const float* __restrict__ Wn1, const float* __restrict__ bn1,
    const float* __restrict__ We1, const float* __restrict__ be1,
    const float* __restrict__ Wg,  const float* __restrict__ bg,
    const float* __restrict__ margin, const float* __restrict__ brisk,
    const unsigned int* __restrict__ amask_words,
    float* __restrict__ base_n, float* __restrict__ base_e,
    float* __restrict__ out_gate, int* __restrict__ flag,
    float* __restrict__ node_delta, float* __restrict__ out2)
{
    __shared__ __align__(16) float sF[2][256];
    __shared__ __align__(16) float sH[2][256];
    __shared__ float red[512];
    __shared__ int cls0, cls1;

    int t = threadIdx.x;
    int w = t >> 8;        // 0/1: row in P1/P2, matrix in P3
    int c = t & 255;
    int b0 = blockIdx.x * 2;
    int b = b0 + w;

    // zero partial accumulators: 256 blocks x 512 thr covers B*N exactly
    {
        int idx = blockIdx.x * 512 + t;
        node_delta[idx] = 0.f;
        ((float4*)out2)[idx] = make_float4(0.f, 0.f, 0.f, 0.f);  // B*E = 4*B*N
    }

    if (blockIdx.x == 0) {
        if (t == 0) { cls0 = 0; cls1 = 0; }
        __syncthreads();
        if (t < 256) {
            unsigned int wd = amask_words[t];
            if (wd != 0u && wd != 1u) {
                if (wd == 0x3f800000u) atomicOr(&cls1, 1);
                else                   atomicOr(&cls0, 1);
            }
        }
        __syncthreads();
        if (t == 0) *flag = cls0 ? 1 : (cls1 ? 2 : 0);
    }

    sF[w][c] = feat[(long)b * D + c];
    __syncthreads();

    // ---- P1: relu(feat @ Wc1 + bc1) -> sH ----
    {
        float acc[4] = {bc1[c], 0.f, 0.f, 0.f};
        const float* Wp = Wc1 + c;
        for (int d0 = 0; d0 < D; d0 += 16) {
            float wv[16];
            #pragma unroll
            for (int k = 0; k < 16; k++) wv[k] = Wp[(long)(d0 + k) * H];
            #pragma unroll
            for (int k = 0; k < 16; k++)
                acc[k & 3] = fmaf(sF[w][d0 + k], wv[k], acc[k & 3]);
        }
        sH[w][c] = fmaxf((acc[0] + acc[1]) + (acc[2] + acc[3]), 0.f);
    }
    __syncthreads();

    // ---- P2: h = relu(A @ Wc2 + bc2) -> sF ----
    {
        float acc[4] = {bc2[c], 0.f, 0.f, 0.f};
        const float* Wp = Wc2 + c;
        for (int d0 = 0; d0 < H; d0 += 16) {
            float wv[16];
            #pragma unroll
            for (int k = 0; k < 16; k++) wv[k] = Wp[(long)(d0 + k) * H];
            #pragma unroll
            for (int k = 0; k < 16; k++)
                acc[k & 3] = fmaf(sH[w][d0 + k], wv[k], acc[k & 3]);
        }
        float a = fmaxf((acc[0] + acc[1]) + (acc[2] + acc[3]), 0.f);
        __syncthreads();
        sF[w][c] = a;                 // sF now holds h for both rows
    }
    __syncthreads();

    // ---- gate per row ----
    red[t] = sF[w][c] * Wg[c];
    __syncthreads();
    for (int s = 128; s > 0; s >>= 1) {
        if (c < s) red[t] += red[t + s];
        __syncthreads();
    }
    if (c == 0) {
        float lg = 1.f / (1.f + expf(-(red[t] + bg[0])));
        out_gate[b] = ((margin[b] < 0.2f) || (brisk[b] > 0.6f) || (lg > 0.5f)) ? 1.f : 0.f;
    }

    // ---- P3: base_n / base_e (thread-half = matrix, both rows) ----
    {
        const float* W3  = w ? (We1 + c) : (Wn1 + c);
        float bias       = w ? be1[c]    : bn1[c];
        float* dst       = w ? base_e    : base_n;
        float aA[2] = {bias, 0.f};
        float aB[2] = {bias, 0.f};
        for (int d0 = 0; d0 < H; d0 += 16) {
            float wv[16];
            #pragma unroll
            for (int k = 0; k < 16; k++) wv[k] = W3[(long)(d0 + k) * H];
            #pragma unroll
            for (int k = 0; k < 16; k++) {
                aA[k & 1] = fmaf(sF[0][d0 + k], wv[k], aA[k & 1]);
                aB[k & 1] = fmaf(sF[1][d0 + k], wv[k], aB[k & 1]);
            }
        }
        dst[(long)b0 * H + c]       = aA[0] + aA[1];
        dst[(long)(b0 + 1) * H + c] = aB[0] + aB[1];
    }
}

// ---------------------------------------------------------------------------
// k_ne: j-split partial MLP. Blocks [0,512): node — row-group rg=bid>>2,
// j-quarter jq=bid&3; wave w = row rg*4+w, 4 items/lane, 64-j loop.
// Blocks [512,2560): edge — row b=(bid-512)>>2, jq=(bid-512)&3; 4 items/thr.
// Partial relu-sums accumulate via atomicAdd into node_delta / out2 (both
// zeroed by k_h). Bias bn2/be2 and gate/mask applied later in k_fin.
// ---------------------------------------------------------------------------
__global__ __launch_bounds__(256) void k_ne(
    const float* __restrict__ cs, const float* __restrict__ coords,
    const float* __restrict__ unc, const int* __restrict__ actions,
    const float* __restrict__ Wn1, const float* __restrict__ Wn2,
    const float* __restrict__ base_n,
    const float* __restrict__ es, const int* __restrict__ edges,
    const float* __restrict__ We1, const float* __restrict__ We2,
    const float* __restrict__ base_e,
    const float* __restrict__ gate,
    float* __restrict__ node_delta, float* __restrict__ out2)
{
    __shared__ __align__(16) float smem[2816];
    int t = threadIdx.x;

    if (blockIdx.x < NODE_GRID) {
        // ================= NODE quarter =================
        int rg = blockIdx.x >> 2;
        int jq = blockIdx.x & 3;
        int b0 = rg * 4;
        float* sB   = smem;          // [4][64] bases
        float* pack = smem + 256;    // [64][12]

        {
            int i = t;
            #pragma unroll
            for (int s = 0; s < 3; s++, i += 256) {
                int j = i / 12, k = i - j * 12;
                int jj = jq * 64 + j;
                float v;
                if (k < 10)      v = Wn1[(long)(H + k) * H + jj];
                else if (k == 10) v = Wn2[jj];
                else             v = 0.f;
                pack[i] = v;
            }
            int r = t >> 6, j = t & 63;
            sB[r * 64 + j] = base_n[(long)(b0 + r) * H + jq * 64 + j];
        }
        __syncthreads();

        int w = t >> 6, lane = t & 63;
        int b = b0 + w;
        float g = gate[b];
        if (g == 0.f) return;    // delta stays 0; k_fin handles

        float f[4][10], acc[4];
        #pragma unroll
        for (int q = 0; q < 4; q++) {
            int n = q * 64 + lane;
            const float4* cp = (const float4*)(coords + ((long)b * N + n) * C);
            float4 c0 = cp[0], c1 = cp[1];
            f[q][0] = c0.x; f[q][1] = c0.y; f[q][2] = c0.z; f[q][3] = c0.w;
            f[q][4] = c1.x; f[q][5] = c1.y; f[q][6] = c1.z; f[q][7] = c1.w;
            f[q][8] = cs[(long)b * N + n];
            int a = actions[(long)b * N + n];
            a = min(max(a, 0), U - 1);
            f[q][9] = unc[(long)b * U + a];
            acc[q] = 0.f;
        }

        const float4* pk = (const float4*)pack;
        const float* sBw = sB + w * 64;
        #pragma unroll 4
        for (int j = 0; j < 64; j++) {
            float4 wa = pk[j * 3 + 0];
            float4 wb = pk[j * 3 + 1];
            float4 wc = pk[j * 3 + 2];
            float bse = sBw[j];
            #pragma unroll
            for (int q = 0; q < 4; q++) {
                float zA = fmaf(f[q][0], wa.x, bse);
                zA = fmaf(f[q][1], wa.y, zA);
                zA = fmaf(f[q][2], wa.z, zA);
                zA = fmaf(f[q][3], wa.w, zA);
                float zB = f[q][4] * wb.x;
                zB = fmaf(f[q][5], wb.y, zB);
                zB = fmaf(f[q][6], wb.z, zB);
                zB = fmaf(f[q][7], wb.w, zB);
                zB = fmaf(f[q][8], wc.x, zB);
                zB = fmaf(f[q][9], wc.y, zB);
                acc[q] = fmaf(fmaxf(zA + zB, 0.f), wc.z, acc[q]);
            }
        }

        #pragma unroll
        for (int q = 0; q < 4; q++)
            atomicAdd(&node_delta[(long)b * N + q * 64 + lane], acc[q]);
    } else {
        // ================= EDGE quarter =================
        int eb = blockIdx.x - NODE_GRID;
        int b = eb >> 2, jq = eb & 3;
        float g = gate[b];
        if (g == 0.f) return;    // delta stays 0; k_fin handles

        float (*sC)[8] = (float (*)[8])smem;   // 2048 floats
        float* pack = smem + 2048;             // [64][12]

        {
            float4* sc4 = (float4*)smem;
            const float4* g4 = (const float4*)(coords + (long)b * N * C);
            sc4[t] = g4[t];
            sc4[t + 256] = g4[t + 256];
            int i = t;
            #pragma unroll
            for (int s = 0; s < 3; s++, i += 256) {
                int j = i / 12, k = i - j * 12;
                int jj = jq * 64 + j;
                float v;
                if (k < 9)        v = We1[(long)(H + k) * H + jj];
                else if (k == 9)  v = We2[jj];
                else if (k == 10) v = base_e[(long)b * H + jj]
                                      + We1[(long)(H + 9) * H + jj];  // emf fold
                else              v = 0.f;
                pack[i] = v;
            }
        }
        __syncthreads();

        float f[4][9], acc[4];
        #pragma unroll
        for (int q = 0; q < 4; q++) {
            int e = t + 256 * q;
            int2 ev = ((const int2*)edges)[(long)b * E + e];
            int s0 = min(max(ev.x, 0), N - 1);
            int d0 = min(max(ev.y, 0), N - 1);
            #pragma unroll
            for (int k = 0; k < 8; k++) f[q][k] = sC[d0][k] - sC[s0][k];
            f[q][8] = es[(long)b * E + e];
            acc[q] = 0.f;
        }

        const float4* pk = (const float4*)pack;
        #pragma unroll 4
        for (int j = 0; j < 64; j++) {
            float4 wa = pk[j * 3 + 0];
            float4 wb = pk[j * 3 + 1];
            float4 wc = pk[j * 3 + 2];
            #pragma unroll
            for (int q = 0; q < 4; q++) {
                float zA = fmaf(f[q][0], wa.x, wc.z);   // base (+w9 fold)
                zA = fmaf(f[q][1], wa.y, zA);
                zA = fmaf(f[q][2], wa.z, zA);
                zA = fmaf(f[q][3], wa.w, zA);
                float zB = f[q][4] * wb.x;
                zB = fmaf(f[q][5], wb.y, zB);
                zB = fmaf(f[q][6], wb.z, zB);
                zB = fmaf(f[q][7], wb.w, zB);
                zB = fmaf(f[q][8], wc.x, zB);
                acc[q] = fmaf(fmaxf(zA + zB, 0.f), wc.y, acc[q]);
            }
        }

        #pragma unroll
        for (int q = 0; q < 4; q++)
            atomicAdd(&out2[(long)b * E + t + 256 * q], acc[q]);
    }
}

// ---------------------------------------------------------------------------
// k_fin: blocks [0,512) node rows: assemble raw scores from partial delta,
// center, top-2 (+index), margin, riskbase. Blocks [512,1024) edge rows:
// assemble refined_edge from partial delta, mean/var -> evar.
// ---------------------------------------------------------------------------
__global__ __launch_bounds__(256) void k_fin(
    const void* __restrict__ amask, const void* __restrict__ emask,
    const int* __restrict__ actions, const float* __restrict__ unc,
    const float* __restrict__ cs, const float* __restrict__ es,
    const float* __restrict__ bn2, const float* __restrict__ be2,
    const float* __restrict__ gate, const int* __restrict__ flagp,
    const float* __restrict__ node_delta,
    float* __restrict__ out0, float* __restrict__ out1,
    float* __restrict__ out2, float* __restrict__ out3,
    float* __restrict__ riskbase, float* __restrict__ evar)
{
    __shared__ float red[256];
    __shared__ int ridx[256];
    int t = threadIdx.x;
    int flag = *flagp;

    if (blockIdx.x < B) {
        // ---- node row ----
        int b = blockIdx.x;
        float g = gate[b];
        float am = mask_val(amask, (long)b * N + t, flag);
        float csv = cs[(long)b * N + t];
        int a = actions[(long)b * N + t];
        a = min(max(a, 0), U - 1);
        float ug = unc[(long)b * U + a];
        float nd = (node_delta[(long)b * N + t] + bn2[0]) * am;
        float raw = (csv + g * 0.1f * nd) * am;

        float sum = block_sum(raw, red);
        float cnt = block_sum(am, red);
        float denom = fmaxf(cnt, 1.f);
        float rs = (raw - sum / denom) * am;
        out0[(long)b * N + t] = rs;

        float masked = (am != 0.f) ? rs : -1e9f;

        red[t] = masked; ridx[t] = t; __syncthreads();
        for (int s = 128; s > 0; s >>= 1) {
            if (t < s) {
                float o = red[t + s]; int oi = ridx[t + s];
                if (o > red[t] || (o == red[t] && oi < ridx[t])) { red[t] = o; ridx[t] = oi; }
            }
            __syncthreads();
        }
        float v1 = red[0]; int i1 = ridx[0]; __syncthreads();

        red[t] = (t == i1) ? -1e9f : masked; __syncthreads();
        for (int s = 128; s > 0; s >>= 1) {
            if (t < s) red[t] = fmaxf(red[t], red[t + s]);
            __syncthreads();
        }
        float v2 = red[0]; __syncthreads();
        float rmargin = v1 - v2;

        float su = block_sum(ug * am, red);

        if (t == 0) {
            out1[b] = rmargin;
            out3[b] = (float)i1;
            float sig = 1.f / (1.f + expf(rmargin));   // sigmoid(-margin)
            riskbase[b] = sig + 0.1f * (su / denom);
        }
    } else {
        // ---- edge row ----
        int b = blockIdx.x - B;
        float g = gate[b];
        float be2v = be2[0];

        float re[4], emv[4];
        #pragma unroll
        for (int q = 0; q < 4; q++) {
            long idx = (long)b * E + t + 256 * q;
            emv[q] = mask_val(emask, idx, flag);
            float delta = out2[idx] + be2v;
            float r = es[idx] + g * 0.1f * delta;
            re[q] = (emv[q] != 0.f) ? r : 0.f;
            out2[idx] = re[q];
        }

        float S1 = 0.f, ce = 0.f;
        #pragma unroll
        for (int q = 0; q < 4; q++) { S1 += re[q]; ce += emv[q]; }
        float S1t = block_sum(S1, red);
        float cet = block_sum(ce, red);
        float mean = S1t / fmaxf(cet, 1.f);
        float v = 0.f;
        #pragma unroll
        for (int q = 0; q < 4; q++) {
            float dd = re[q] - mean;
            v = fmaf(emv[q] * dd, dd, v);
        }
        float vt = block_sum(v, red);
        if (t == 0) {
            float var = vt / fmaxf(cet, 1.f);
            evar[b] = (cet > 1.f) ? var : 0.f;
        }
    }
}

// ---------------------------------------------------------------------------
// k_risk: out4 = clip(riskbase + 0.2*evar, 0, 1)
// ---------------------------------------------------------------------------
__global__ __launch_bounds__(256) void k_risk(
    const float* __restrict__ riskbase, const float* __restrict__ evar,
    float* __restrict__ out4)
{
    int b = blockIdx.x * 256 + threadIdx.x;
    float r = riskbase[b] + 0.2f * evar[b];
    out4[b] = fminf(fmaxf(r, 0.f), 1.f);
}

// ---------------------------------------------------------------------------
extern "C" void kernel_launch(void* const* d_in, const int* in_sizes, int n_in,
                              void* d_out, int out_size, void* d_ws, size_t ws_size,
                              hipStream_t stream) {
    const float* feat   = (const float*)d_in[0];
    const float* cs     = (const float*)d_in[1];
    const float* marg   = (const float*)d_in[2];
    const float* brisk  = (const float*)d_in[3];
    const float* es     = (const float*)d_in[4];
    const float* coords = (const float*)d_in[5];
    const float* unc    = (const float*)d_in[6];
    const float* Wc1    = (const float*)d_in[7];
    const float* bc1    = (const float*)d_in[8];
    const float* Wc2    = (const float*)d_in[9];
    const float* bc2    = (const float*)d_in[10];
    const float* Wn1    = (const float*)d_in[11];
    const float* bn1    = (const float*)d_in[12];
    const float* Wn2    = (const float*)d_in[13];
    const float* bn2    = (const float*)d_in[14];
    const float* We1    = (const float*)d_in[15];
    const float* be1    = (const float*)d_in[16];
    const float* We2    = (const float*)d_in[17];
    const float* be2    = (const float*)d_in[18];
    const float* Wg     = (const float*)d_in[19];
    const float* bg     = (const float*)d_in[20];
    const void*  amask  = d_in[21];
    const void*  emask  = d_in[22];
    const int*   actions= (const int*)d_in[23];
    const int*   edges  = (const int*)d_in[24];

    float* out0 = (float*)d_out;           // refined_scores (B,N)
    float* out1 = out0 + (long)B * N;      // refined_margin (B,)
    float* out2 = out1 + B;                // refined_edge (B,E)
    float* out3 = out2 + (long)B * E;      // top_idx (B,) as float
    float* out4 = out3 + B;                // refined_risk (B,)
    float* out5 = out4 + B;                // refine_gate (B,)

    float* base_n     = (float*)d_ws;                  // B*H
    float* base_e     = base_n + (long)B * H;          // B*H
    float* node_delta = base_e + (long)B * H;          // B*N
    float* riskbase   = node_delta + (long)B * N;      // B
    float* evar       = riskbase + B;                  // B
    int*   flag       = (int*)(evar + B);

    k_h<<<B / 2, 512, 0, stream>>>(feat, Wc1, bc1, Wc2, bc2, Wn1, bn1, We1, be1,
                                   Wg, bg, marg, brisk,
                                   (const unsigned int*)amask,
                                   base_n, base_e, out5, flag,
                                   node_delta, out2);
    k_ne<<<NODE_GRID + EDGE_GRID, 256, 0, stream>>>(
        cs, coords, unc, actions,
        Wn1, Wn2, base_n,
        es, edges,
        We1, We2, base_e,
        out5, node_delta, out2);
    k_fin<<<2 * B, 256, 0, stream>>>(amask, emask, actions, unc, cs, es,
                                     bn2, be2, out5, flag, node_delta,
                                     out0, out1, out2, out3, riskbase, evar);
    k_risk<<<2, 256, 0, stream>>>(riskbase, evar, out4);
}